// Round 2
// baseline (581.877 us; speedup 1.0000x reference)
//
#include <hip/hip_runtime.h>
#include <cstdint>
#include <cstddef>

// ---------------------------------------------------------------------------
// Hyena operator, MI355X. Pipeline:
//  cast(u,W1,W2)->bf16 ; GEMM1 (bf16 MFMA, writes upT[1152][16384] bf16 +bias)
//  fftconv: per channel c (1536 blocks, 1024 thr): DIF-FFT(k_c) -> K in regs,
//           pack (fused depthwise conv3 + pre-gate, both batches as re/im),
//           DIF-FFT, pointwise*K (bit-rev space, conj), DIT-FFT, finalize
//           (+conv_bias skip, post-gate x0) -> z[3072][8192] bf16
//  transpose z -> zt[16384][1536] ; GEMM2 (bf16 MFMA, f32 out + bias) -> d_out
// ---------------------------------------------------------------------------

using s16x8 = __attribute__((ext_vector_type(8))) short;
using f32x4 = __attribute__((ext_vector_type(4))) float;

__device__ __forceinline__ float bfu2f(unsigned short h) {
  union { unsigned int u; float f; } a; a.u = ((unsigned int)h) << 16; return a.f;
}
__device__ __forceinline__ unsigned short f2bf(float f) {
  union { float f; unsigned int u; } a; a.f = f;
  unsigned int r = a.u + 0x7fffu + ((a.u >> 16) & 1u);
  return (unsigned short)(r >> 16);
}
__device__ __forceinline__ float2 cmul(float2 a, float2 b) {
  return make_float2(a.x*b.x - a.y*b.y, a.x*b.y + a.y*b.x);
}
__device__ __forceinline__ float2 cadd(float2 a, float2 b) { return make_float2(a.x+b.x, a.y+b.y); }
__device__ __forceinline__ float2 csub(float2 a, float2 b) { return make_float2(a.x-b.x, a.y-b.y); }
// LDS bank swizzle at float2 granularity: conflict-free (4 lanes per 16-slot
// bank class) for all power-of-2 strides q=1..4096 and for consecutive access.
__device__ __forceinline__ int SW(int p) { return p ^ ((p >> 4) & 15); }

// ---------------- cast f32 -> bf16 (vectorized) ----------------
__global__ __launch_bounds__(256)
void cast_f32_to_bf16(const float* __restrict__ src, unsigned short* __restrict__ dst, const int n) {
  const int i = (blockIdx.x * 256 + threadIdx.x) * 4;
  if (i < n) {
    const float4 v = *(const float4*)(src + i);
    ushort4 o;
    o.x = f2bf(v.x); o.y = f2bf(v.y); o.z = f2bf(v.z); o.w = f2bf(v.w);
    *(ushort4*)(dst + i) = o;
  }
}

// ---------------- bf16 GEMM: C[m][n] = sum_k A[m][k]*B[n][k] + bias[n] ------
// TRANS=1: store bf16 C^T at Ct[n*M+m].  TRANS=0: store f32 C[m*N+n].
template<int TRANS>
__global__ __launch_bounds__(256)
void gemm_bt(const unsigned short* __restrict__ A, const unsigned short* __restrict__ B,
             const float* __restrict__ bias, void* __restrict__ Cout,
             const int M, const int N, const int K) {
  __shared__ unsigned short As[128 * 32];
  __shared__ unsigned short Bs[128 * 32];
  const int tid  = threadIdx.x;
  const int lane = tid & 63;
  const int wave = tid >> 6;
  const int m0 = blockIdx.x * 128;
  const int n0 = blockIdx.y * 128;
  const int wm = (wave >> 1) * 64;
  const int wn = (wave & 1) * 64;
  f32x4 acc[4][4] = {};

  const int srow = lane >> 2;        // 0..15 within 16-row group
  const int scol = (lane & 3) * 8;   // 0,8,16,24

  for (int k0 = 0; k0 < K; k0 += 32) {
    __syncthreads();
#pragma unroll
    for (int pass = 0; pass < 2; ++pass) {
      const int rbase = pass * 64 + wave * 16;
      const unsigned short* ga = A + (size_t)(m0 + rbase + srow) * K + k0 + scol;
      const unsigned short* gb = B + (size_t)(n0 + rbase + srow) * K + k0 + scol;
      __builtin_amdgcn_global_load_lds((__attribute__((address_space(1))) void*)ga,
                                       (__attribute__((address_space(3))) void*)(As + rbase * 32), 16, 0, 0);
      __builtin_amdgcn_global_load_lds((__attribute__((address_space(1))) void*)gb,
                                       (__attribute__((address_space(3))) void*)(Bs + rbase * 32), 16, 0, 0);
    }
    __syncthreads();
    s16x8 af[4], bfr[4];
#pragma unroll
    for (int i = 0; i < 4; ++i) {
      af[i]  = *(const s16x8*)(As + (wm + i * 16 + (lane & 15)) * 32 + (lane >> 4) * 8);
      bfr[i] = *(const s16x8*)(Bs + (wn + i * 16 + (lane & 15)) * 32 + (lane >> 4) * 8);
    }
#pragma unroll
    for (int mi = 0; mi < 4; ++mi)
#pragma unroll
      for (int ni = 0; ni < 4; ++ni)
        acc[mi][ni] = __builtin_amdgcn_mfma_f32_16x16x32_bf16(af[mi], bfr[ni], acc[mi][ni], 0, 0, 0);
  }
#pragma unroll
  for (int mi = 0; mi < 4; ++mi) {
#pragma unroll
    for (int ni = 0; ni < 4; ++ni) {
      const int col  = n0 + wn + ni * 16 + (lane & 15);
      const int row0 = m0 + wm + mi * 16 + (lane >> 4) * 4;
      const float bv = bias[col];
      if (TRANS) {
        unsigned short* Ct = (unsigned short*)Cout;
        ushort4 o;
        o.x = f2bf(acc[mi][ni][0] + bv);
        o.y = f2bf(acc[mi][ni][1] + bv);
        o.z = f2bf(acc[mi][ni][2] + bv);
        o.w = f2bf(acc[mi][ni][3] + bv);
        *(ushort4*)(Ct + (size_t)col * M + row0) = o;
      } else {
        float* C = (float*)Cout;
#pragma unroll
        for (int rr = 0; rr < 4; ++rr)
          C[(size_t)(row0 + rr) * N + col] = acc[mi][ni][rr] + bv;
      }
    }
  }
}

// ---------------- in-LDS FFT, N=16384 complex, 1024 threads -----------------
// Radix-2 algorithm with pairs of stages fused (radix-4 butterflies), so the
// input/output permutation is the pure 14-bit bit-reversal -- never
// materialized, because forward(DIF: nat->br) and inverse(DIT: br->nat)
// cancel; the pointwise multiply is order-agnostic.
__device__ __forceinline__ void dif_bfly(float2* __restrict__ buf, const int p0, const int q,
                                         const float2 w1, const float2 w2) {
  float2 x0 = buf[SW(p0)];
  float2 x1 = buf[SW(p0 + q)];
  float2 x2 = buf[SW(p0 + 2 * q)];
  float2 x3 = buf[SW(p0 + 3 * q)];
  const float2 ta = cadd(x0, x2), tb = csub(x0, x2);
  const float2 ua = cadd(x1, x3), ub = csub(x1, x3);
  const float2 v02 = cmul(tb, w1);
  float2 v13 = cmul(ub, w1);
  v13 = make_float2(v13.y, -v13.x);            // * (-i)
  buf[SW(p0)]         = cadd(ta, ua);
  buf[SW(p0 + q)]     = cmul(csub(ta, ua), w2);
  buf[SW(p0 + 2 * q)] = cadd(v02, v13);
  buf[SW(p0 + 3 * q)] = cmul(csub(v02, v13), w2);
}

__device__ __forceinline__ void dit_bfly(float2* __restrict__ buf, const int p0, const int q,
                                         const float2 w1, const float2 w2) {
  float2 x0 = buf[SW(p0)];
  float2 x1 = buf[SW(p0 + q)];
  float2 x2 = buf[SW(p0 + 2 * q)];
  float2 x3 = buf[SW(p0 + 3 * q)];
  const float2 t1 = cmul(x1, w2);
  const float2 y0 = cadd(x0, t1), y1 = csub(x0, t1);
  const float2 t3 = cmul(x3, w2);
  const float2 y2 = cadd(x2, t3), y3 = csub(x2, t3);
  const float2 t  = cmul(y2, w1);
  float2 t4 = cmul(y3, w1);
  t4 = make_float2(t4.y, -t4.x);               // * (-i)
  buf[SW(p0)]         = cadd(y0, t);
  buf[SW(p0 + q)]     = cadd(y1, t4);
  buf[SW(p0 + 2 * q)] = csub(y0, t);
  buf[SW(p0 + 3 * q)] = csub(y1, t4);
}

__device__ __forceinline__ void dif_fft(float2* __restrict__ buf, const int tid) {
  for (int r = 0; r < 7; ++r) {
    const int qs = 12 - 2 * r;          // q = m/4, m = 1<<(14-2r)
    const int q  = 1 << qs;
    const float angf = -6.2831853071795864769f / (float)(4 << qs);
    if (qs <= 10) {                     // q <= 1024: j invariant across iters
      const int j = tid & (q - 1);
      float sn, cs;
      __sincosf(angf * (float)j, &sn, &cs);
      const float2 w1 = make_float2(cs, sn);
      const float2 w2 = cmul(w1, w1);
#pragma unroll
      for (int it = 0; it < 4; ++it) {
        const int id = tid + it * 1024;
        const int p0 = ((id >> qs) << (qs + 2)) + j;
        dif_bfly(buf, p0, q, w1, w2);
      }
    } else {
#pragma unroll
      for (int it = 0; it < 4; ++it) {
        const int id = tid + it * 1024;
        const int j  = id & (q - 1);
        const int p0 = ((id >> qs) << (qs + 2)) + j;
        float sn, cs;
        __sincosf(angf * (float)j, &sn, &cs);
        const float2 w1 = make_float2(cs, sn);
        dif_bfly(buf, p0, q, w1, cmul(w1, w1));
      }
    }
    __syncthreads();
  }
}

__device__ __forceinline__ void dit_fft(float2* __restrict__ buf, const int tid) {
  for (int r = 0; r < 7; ++r) {
    const int qs = 2 * r;               // q = m/2, m = 1<<(2r+1)
    const int q  = 1 << qs;
    const float angf = -6.2831853071795864769f / (float)(4 << qs);
    if (qs <= 10) {                     // j invariant across iters
      const int j = tid & (q - 1);
      float sn, cs;
      __sincosf(angf * (float)j, &sn, &cs);
      const float2 w1 = make_float2(cs, sn);
      const float2 w2 = cmul(w1, w1);
#pragma unroll
      for (int it = 0; it < 4; ++it) {
        const int id = tid + it * 1024;
        const int p0 = ((id >> qs) << (qs + 2)) + j;
        dit_bfly(buf, p0, q, w1, w2);
      }
    } else {
#pragma unroll
      for (int it = 0; it < 4; ++it) {
        const int id = tid + it * 1024;
        const int j  = id & (q - 1);
        const int p0 = ((id >> qs) << (qs + 2)) + j;
        float sn, cs;
        __sincosf(angf * (float)j, &sn, &cs);
        const float2 w1 = make_float2(cs, sn);
        dit_bfly(buf, p0, q, w1, cmul(w1, w1));
      }
    }
    __syncthreads();
  }
}

// ---------------- fused shortconv + gate + FFT long conv --------------------
__global__ __launch_bounds__(1024, 4)
void hyena_fftconv(const unsigned short* __restrict__ upT,  // [1152][16384] bf16
                   const float* __restrict__ kmat,          // [1536][8192]
                   const float* __restrict__ short_w,       // [4608][3]
                   const float* __restrict__ short_b,       // [4608]
                   const float* __restrict__ conv_bias,     // [1536]
                   unsigned short* __restrict__ z) {        // [3072][8192] bf16
  __shared__ float2 buf[16384];                              // 128 KB
  const int tid = threadIdx.x;
  const int c   = blockIdx.x;                                // channel 0..1535

  // ---- K spectrum (zero-padded real kernel, full complex DFT, br order) ----
  const float* kr = kmat + (size_t)c * 8192;
#pragma unroll
  for (int i = 0; i < 16; ++i) {
    const int n = tid + i * 1024;
    float2 v = make_float2(0.f, 0.f);
    if (n < 8192) v.x = kr[n];
    buf[SW(n)] = v;
  }
  __syncthreads();
  dif_fft(buf, tid);
  float2 kf[16];
#pragma unroll
  for (int i = 0; i < 16; ++i) kf[i] = buf[SW(tid + i * 1024)];
  __syncthreads();

  // ---- pack: fused depthwise conv3 + pre-gate; batch0 = re, batch1 = im ----
  const int c0 = c % 1152;
  const int c1 = (c + 384) % 1152;
  const int c2 = (c + 768) % 1152;
  const unsigned short* r0 = upT + (size_t)c0 * 16384;
  const unsigned short* r1 = upT + (size_t)c1 * 16384;
  const unsigned short* r2 = upT + (size_t)c2 * 16384;
  float w0[3], w1v[3], w2v[3];
#pragma unroll
  for (int j = 0; j < 3; ++j) {
    w0[j]  = short_w[(size_t)c * 3 + j];
    w1v[j] = short_w[(size_t)(1536 + c) * 3 + j];
    w2v[j] = short_w[(size_t)(3072 + c) * 3 + j];
  }
  const float b0 = short_b[c], b1s = short_b[1536 + c], b2s = short_b[3072 + c];
  float x0a[8], x0b[8], vpa[8], vpb[8];
#pragma unroll
  for (int i = 0; i < 8; ++i) {
    const int n = tid + i * 1024;
    float s0a = b0, s1a = b1s, s2a = b2s;
    float s0b = b0, s1b = b1s, s2b = b2s;
#pragma unroll
    for (int j = 0; j < 3; ++j) {
      const int t = n - 2 + j;
      if (t >= 0) {
        s0a += w0[j]  * bfu2f(r0[t]);
        s1a += w1v[j] * bfu2f(r1[t]);
        s2a += w2v[j] * bfu2f(r2[t]);
        s0b += w0[j]  * bfu2f(r0[8192 + t]);
        s1b += w1v[j] * bfu2f(r1[8192 + t]);
        s2b += w2v[j] * bfu2f(r2[8192 + t]);
      }
    }
    x0a[i] = s0a; x0b[i] = s0b;
    vpa[i] = s2a * s1a; vpb[i] = s2b * s1b;
    buf[SW(n)] = make_float2(vpa[i], vpb[i]);
  }
#pragma unroll
  for (int i = 8; i < 16; ++i) buf[SW(tid + i * 1024)] = make_float2(0.f, 0.f);
  __syncthreads();
  dif_fft(buf, tid);

  // ---- pointwise multiply by K, store conj for inverse-via-forward-DIT ----
#pragma unroll
  for (int i = 0; i < 16; ++i) {
    const int p = SW(tid + i * 1024);
    const float2 a = buf[p], b = kf[i];
    buf[p] = make_float2(a.x * b.x - a.y * b.y, -(a.x * b.y + a.y * b.x));
  }
  __syncthreads();
  dit_fft(buf, tid);

  // ---- finalize: y = conj(F)/N ; add conv_bias skip ; post-gate by x0 ----
  const float cb  = conv_bias[c];
  const float inv = 1.0f / 16384.0f;
  unsigned short* za = z + (size_t)c * 8192;
  unsigned short* zb = z + (size_t)(1536 + c) * 8192;
#pragma unroll
  for (int i = 0; i < 8; ++i) {
    const int n = tid + i * 1024;
    const float2 F = buf[SW(n)];
    const float ya =  F.x * inv;
    const float yb = -F.y * inv;
    za[n] = f2bf((ya + vpa[i] * cb) * x0a[i]);
    zb[n] = f2bf((yb + vpb[i] * cb) * x0b[i]);
  }
}

// ---------------- transpose z[3072][8192] -> zt[16384][1536] ----------------
__global__ __launch_bounds__(256)
void transpose_z(const unsigned short* __restrict__ z, unsigned short* __restrict__ zt) {
  __shared__ unsigned short tile[64][65];
  const int tid = threadIdx.x;
  const int ct = blockIdx.x;   // 0..23  (c tiles)
  const int tt = blockIdx.y;   // 0..127 (t tiles)
  const int b  = blockIdx.z;   // 0..1
#pragma unroll
  for (int p = 0; p < 2; ++p) {
    const int idx = p * 256 + tid;
    const int row = idx >> 3;  // local c
    const int c8  = idx & 7;
    const uint4 v = *(const uint4*)(z + (size_t)(b * 1536 + ct * 64 + row) * 8192 + tt * 64 + c8 * 8);
    unsigned short* tp = &tile[row][c8 * 8];
    tp[0] = (unsigned short)(v.x & 0xffff); tp[1] = (unsigned short)(v.x >> 16);
    tp[2] = (unsigned short)(v.y & 0xffff); tp[3] = (unsigned short)(v.y >> 16);
    tp[4] = (unsigned short)(v.z & 0xffff); tp[5] = (unsigned short)(v.z >> 16);
    tp[6] = (unsigned short)(v.w & 0xffff); tp[7] = (unsigned short)(v.w >> 16);
  }
  __syncthreads();
#pragma unroll
  for (int p = 0; p < 2; ++p) {
    const int idx  = p * 256 + tid;
    const int trow = idx >> 3;  // local t
    const int cc   = idx & 7;
    uint4 o;
    o.x = (unsigned)tile[cc * 8 + 0][trow] | ((unsigned)tile[cc * 8 + 1][trow] << 16);
    o.y = (unsigned)tile[cc * 8 + 2][trow] | ((unsigned)tile[cc * 8 + 3][trow] << 16);
    o.z = (unsigned)tile[cc * 8 + 4][trow] | ((unsigned)tile[cc * 8 + 5][trow] << 16);
    o.w = (unsigned)tile[cc * 8 + 6][trow] | ((unsigned)tile[cc * 8 + 7][trow] << 16);
    *(uint4*)(zt + (size_t)(b * 8192 + tt * 64 + trow) * 1536 + ct * 64 + cc * 8) = o;
  }
}

// ---------------------------------------------------------------------------
extern "C" void kernel_launch(void* const* d_in, const int* in_sizes, int n_in,
                              void* d_out, int out_size, void* d_ws, size_t ws_size,
                              hipStream_t stream) {
  const float* u   = (const float*)d_in[0];   // [2,8192,768]
  const float* w1  = (const float*)d_in[1];   // [1152,768]
  const float* b1  = (const float*)d_in[2];   // [1152]
  const float* sw  = (const float*)d_in[3];   // [4608,1,3]
  const float* sb  = (const float*)d_in[4];   // [4608]
  const float* km  = (const float*)d_in[5];   // [1536,8192]
  const float* cb  = (const float*)d_in[6];   // [1536]
  const float* w2  = (const float*)d_in[7];   // [768,1536]
  const float* b2  = (const float*)d_in[8];   // [768]
  float* outp = (float*)d_out;                // [2,8192,768]

  char* ws = (char*)d_ws;
  unsigned short* u_bf  = (unsigned short*)(ws);               // 25165824 B
  unsigned short* w1_bf = (unsigned short*)(ws + 25165824);    //  1769472 B
  unsigned short* w2_bf = (unsigned short*)(ws + 26935296);    //  2359296 B
  unsigned short* upT   = (unsigned short*)(ws + 29294592);    // 37748736 B
  unsigned short* zbuf  = (unsigned short*)(ws + 67043328);    // 50331648 B
  unsigned short* ztb   = (unsigned short*)(ws + 117374976);   // 50331648 B

  cast_f32_to_bf16<<<12288, 256, 0, stream>>>(u,  u_bf,  12582912);
  cast_f32_to_bf16<<<  864, 256, 0, stream>>>(w1, w1_bf,   884736);
  cast_f32_to_bf16<<< 1152, 256, 0, stream>>>(w2, w2_bf,  1179648);

  dim3 g1(128, 9);
  gemm_bt<1><<<g1, 256, 0, stream>>>(u_bf, w1_bf, b1, upT, 16384, 1152, 768);

  hyena_fftconv<<<1536, 1024, 0, stream>>>(upT, km, sw, sb, cb, zbuf);

  transpose_z<<<dim3(24, 128, 2), 256, 0, stream>>>(zbuf, ztb);

  dim3 g2(128, 6);
  gemm_bt<0><<<g2, 256, 0, stream>>>(ztb, w2_bf, b2, outp, 16384, 768, 1536);
}

// Round 3
// 486.817 us; speedup vs baseline: 1.1953x; 1.1953x over previous
//
#include <hip/hip_runtime.h>
#include <cstdint>
#include <cstddef>

// ---------------------------------------------------------------------------
// Hyena operator, MI355X.
//  cast(u,W1,W2)->bf16 ; GEMM1 (bf16 MFMA, writes upT[1152][16384] bf16 +bias)
//  fft_k: per channel, DIF-FFT(zero-padded k_c) -> Kf stored RAW (swizzled
//         physical layout) to workspace (f32x2 or bf16x2 per ws_size).
//  fftconv: pack (fused depthwise conv3 + pre-gate, batch0/1 as re/im),
//           DIF-FFT, streamed pointwise*Kf (raw physical index, conj),
//           DIT-FFT, finalize (+conv_bias skip, post-gate) -> z[3072][8192]
//  transpose z -> zt[16384][1536] ; GEMM2 (bf16 MFMA, f32 out+bias) -> d_out
// Fallback (small ws): monolithic 512-thread kernel with K-FFT in-kernel.
// ---------------------------------------------------------------------------

using s16x8 = __attribute__((ext_vector_type(8))) short;
using f32x4 = __attribute__((ext_vector_type(4))) float;

__device__ __forceinline__ float bfu2f(unsigned short h) {
  union { unsigned int u; float f; } a; a.u = ((unsigned int)h) << 16; return a.f;
}
__device__ __forceinline__ unsigned short f2bf(float f) {
  union { float f; unsigned int u; } a; a.f = f;
  unsigned int r = a.u + 0x7fffu + ((a.u >> 16) & 1u);
  return (unsigned short)(r >> 16);
}
__device__ __forceinline__ float2 cmul(float2 a, float2 b) {
  return make_float2(a.x*b.x - a.y*b.y, a.x*b.y + a.y*b.x);
}
__device__ __forceinline__ float2 cadd(float2 a, float2 b) { return make_float2(a.x+b.x, a.y+b.y); }
__device__ __forceinline__ float2 csub(float2 a, float2 b) { return make_float2(a.x-b.x, a.y-b.y); }
// LDS bank swizzle at float2 granularity; involution (bits 4..7 unchanged),
// 4 lanes per bank-pair class (the b64 floor) for all pow-2 strides.
__device__ __forceinline__ int SW(int p) { return p ^ ((p >> 4) & 15); }

// ---------------- cast f32 -> bf16 (vectorized) ----------------
__global__ __launch_bounds__(256)
void cast_f32_to_bf16(const float* __restrict__ src, unsigned short* __restrict__ dst, const int n) {
  const int i = (blockIdx.x * 256 + threadIdx.x) * 4;
  if (i < n) {
    const float4 v = *(const float4*)(src + i);
    ushort4 o;
    o.x = f2bf(v.x); o.y = f2bf(v.y); o.z = f2bf(v.z); o.w = f2bf(v.w);
    *(ushort4*)(dst + i) = o;
  }
}

// ---------------- bf16 GEMM: C[m][n] = sum_k A[m][k]*B[n][k] + bias[n] ------
template<int TRANS>
__global__ __launch_bounds__(256)
void gemm_bt(const unsigned short* __restrict__ A, const unsigned short* __restrict__ B,
             const float* __restrict__ bias, void* __restrict__ Cout,
             const int M, const int N, const int K) {
  __shared__ unsigned short As[128 * 32];
  __shared__ unsigned short Bs[128 * 32];
  const int tid  = threadIdx.x;
  const int lane = tid & 63;
  const int wave = tid >> 6;
  const int m0 = blockIdx.x * 128;
  const int n0 = blockIdx.y * 128;
  const int wm = (wave >> 1) * 64;
  const int wn = (wave & 1) * 64;
  f32x4 acc[4][4] = {};

  const int srow = lane >> 2;
  const int scol = (lane & 3) * 8;

  for (int k0 = 0; k0 < K; k0 += 32) {
    __syncthreads();
#pragma unroll
    for (int pass = 0; pass < 2; ++pass) {
      const int rbase = pass * 64 + wave * 16;
      const unsigned short* ga = A + (size_t)(m0 + rbase + srow) * K + k0 + scol;
      const unsigned short* gb = B + (size_t)(n0 + rbase + srow) * K + k0 + scol;
      __builtin_amdgcn_global_load_lds((__attribute__((address_space(1))) void*)ga,
                                       (__attribute__((address_space(3))) void*)(As + rbase * 32), 16, 0, 0);
      __builtin_amdgcn_global_load_lds((__attribute__((address_space(1))) void*)gb,
                                       (__attribute__((address_space(3))) void*)(Bs + rbase * 32), 16, 0, 0);
    }
    __syncthreads();
    s16x8 af[4], bfr[4];
#pragma unroll
    for (int i = 0; i < 4; ++i) {
      af[i]  = *(const s16x8*)(As + (wm + i * 16 + (lane & 15)) * 32 + (lane >> 4) * 8);
      bfr[i] = *(const s16x8*)(Bs + (wn + i * 16 + (lane & 15)) * 32 + (lane >> 4) * 8);
    }
#pragma unroll
    for (int mi = 0; mi < 4; ++mi)
#pragma unroll
      for (int ni = 0; ni < 4; ++ni)
        acc[mi][ni] = __builtin_amdgcn_mfma_f32_16x16x32_bf16(af[mi], bfr[ni], acc[mi][ni], 0, 0, 0);
  }
#pragma unroll
  for (int mi = 0; mi < 4; ++mi) {
#pragma unroll
    for (int ni = 0; ni < 4; ++ni) {
      const int col  = n0 + wn + ni * 16 + (lane & 15);
      const int row0 = m0 + wm + mi * 16 + (lane >> 4) * 4;
      const float bv = bias[col];
      if (TRANS) {
        unsigned short* Ct = (unsigned short*)Cout;
        ushort4 o;
        o.x = f2bf(acc[mi][ni][0] + bv);
        o.y = f2bf(acc[mi][ni][1] + bv);
        o.z = f2bf(acc[mi][ni][2] + bv);
        o.w = f2bf(acc[mi][ni][3] + bv);
        *(ushort4*)(Ct + (size_t)col * M + row0) = o;
      } else {
        float* C = (float*)Cout;
#pragma unroll
        for (int rr = 0; rr < 4; ++rr)
          C[(size_t)(row0 + rr) * N + col] = acc[mi][ni][rr] + bv;
      }
    }
  }
}

// ---------------- in-LDS FFT, N=16384 complex, NTHR threads -----------------
__device__ __forceinline__ void dif_bfly(float2* __restrict__ buf, const int p0, const int q,
                                         const float2 w1, const float2 w2) {
  float2 x0 = buf[SW(p0)];
  float2 x1 = buf[SW(p0 + q)];
  float2 x2 = buf[SW(p0 + 2 * q)];
  float2 x3 = buf[SW(p0 + 3 * q)];
  const float2 ta = cadd(x0, x2), tb = csub(x0, x2);
  const float2 ua = cadd(x1, x3), ub = csub(x1, x3);
  const float2 v02 = cmul(tb, w1);
  float2 v13 = cmul(ub, w1);
  v13 = make_float2(v13.y, -v13.x);            // * (-i)
  buf[SW(p0)]         = cadd(ta, ua);
  buf[SW(p0 + q)]     = cmul(csub(ta, ua), w2);
  buf[SW(p0 + 2 * q)] = cadd(v02, v13);
  buf[SW(p0 + 3 * q)] = cmul(csub(v02, v13), w2);
}

__device__ __forceinline__ void dit_bfly(float2* __restrict__ buf, const int p0, const int q,
                                         const float2 w1, const float2 w2) {
  float2 x0 = buf[SW(p0)];
  float2 x1 = buf[SW(p0 + q)];
  float2 x2 = buf[SW(p0 + 2 * q)];
  float2 x3 = buf[SW(p0 + 3 * q)];
  const float2 t1 = cmul(x1, w2);
  const float2 y0 = cadd(x0, t1), y1 = csub(x0, t1);
  const float2 t3 = cmul(x3, w2);
  const float2 y2 = cadd(x2, t3), y3 = csub(x2, t3);
  const float2 t  = cmul(y2, w1);
  float2 t4 = cmul(y3, w1);
  t4 = make_float2(t4.y, -t4.x);               // * (-i)
  buf[SW(p0)]         = cadd(y0, t);
  buf[SW(p0 + q)]     = cadd(y1, t4);
  buf[SW(p0 + 2 * q)] = csub(y0, t);
  buf[SW(p0 + 3 * q)] = csub(y1, t4);
}

template<int NTHR>
__device__ __forceinline__ void dif_fft(float2* __restrict__ buf, const int tid) {
  constexpr int ITERS = 4096 / NTHR;
  for (int r = 0; r < 7; ++r) {
    const int qs = 12 - 2 * r;          // q = m/4, m = 1<<(14-2r)
    const int q  = 1 << qs;
    const float angf = -6.2831853071795864769f / (float)(4 << qs);
    if (q <= NTHR) {                    // j invariant across iters
      const int j = tid & (q - 1);
      float sn, cs;
      __sincosf(angf * (float)j, &sn, &cs);
      const float2 w1 = make_float2(cs, sn);
      const float2 w2 = cmul(w1, w1);
#pragma unroll
      for (int it = 0; it < ITERS; ++it) {
        const int id = tid + it * NTHR;
        const int p0 = ((id >> qs) << (qs + 2)) + j;
        dif_bfly(buf, p0, q, w1, w2);
      }
    } else {
#pragma unroll
      for (int it = 0; it < ITERS; ++it) {
        const int id = tid + it * NTHR;
        const int j  = id & (q - 1);
        const int p0 = ((id >> qs) << (qs + 2)) + j;
        float sn, cs;
        __sincosf(angf * (float)j, &sn, &cs);
        const float2 w1 = make_float2(cs, sn);
        dif_bfly(buf, p0, q, w1, cmul(w1, w1));
      }
    }
    __syncthreads();
  }
}

template<int NTHR>
__device__ __forceinline__ void dit_fft(float2* __restrict__ buf, const int tid) {
  constexpr int ITERS = 4096 / NTHR;
  for (int r = 0; r < 7; ++r) {
    const int qs = 2 * r;               // q = m/2, m = 1<<(2r+1)
    const int q  = 1 << qs;
    const float angf = -6.2831853071795864769f / (float)(4 << qs);
    if (q <= NTHR) {
      const int j = tid & (q - 1);
      float sn, cs;
      __sincosf(angf * (float)j, &sn, &cs);
      const float2 w1 = make_float2(cs, sn);
      const float2 w2 = cmul(w1, w1);
#pragma unroll
      for (int it = 0; it < ITERS; ++it) {
        const int id = tid + it * NTHR;
        const int p0 = ((id >> qs) << (qs + 2)) + j;
        dit_bfly(buf, p0, q, w1, w2);
      }
    } else {
#pragma unroll
      for (int it = 0; it < ITERS; ++it) {
        const int id = tid + it * NTHR;
        const int j  = id & (q - 1);
        const int p0 = ((id >> qs) << (qs + 2)) + j;
        float sn, cs;
        __sincosf(angf * (float)j, &sn, &cs);
        const float2 w1 = make_float2(cs, sn);
        dit_bfly(buf, p0, q, w1, cmul(w1, w1));
      }
    }
    __syncthreads();
  }
}

// ---------------- K-spectrum precompute: store RAW physical layout ----------
template<int KF_BF16>
__global__ __launch_bounds__(1024)
void fft_k_kernel(const float* __restrict__ kmat, void* __restrict__ Kf) {
  __shared__ float2 buf[16384];                              // 128 KB
  const int tid = threadIdx.x;
  const int c   = blockIdx.x;
  const float* kr = kmat + (size_t)c * 8192;
#pragma unroll
  for (int i = 0; i < 16; ++i) {
    const int n = tid + i * 1024;
    float2 v = make_float2(0.f, 0.f);
    if (n < 8192) v.x = kr[n];
    buf[SW(n)] = v;
  }
  __syncthreads();
  dif_fft<1024>(buf, tid);
  if (KF_BF16) {
    ushort2* o = (ushort2*)Kf + (size_t)c * 16384;
#pragma unroll
    for (int i = 0; i < 16; ++i) {
      const int n = tid + i * 1024;
      const float2 v = buf[n];
      o[n] = make_ushort2(f2bf(v.x), f2bf(v.y));
    }
  } else {
    float2* o = (float2*)Kf + (size_t)c * 16384;
#pragma unroll
    for (int i = 0; i < 16; ++i) {
      const int n = tid + i * 1024;
      o[n] = buf[n];
    }
  }
}

// ---------------- main: pack + fwd FFT + streamed pointwise + inv FFT -------
template<int KF_BF16>
__global__ __launch_bounds__(1024)
void hyena_fftconv_split(const unsigned short* __restrict__ upT,  // [1152][16384]
                         const void* __restrict__ Kf,
                         const float* __restrict__ short_w,
                         const float* __restrict__ short_b,
                         const float* __restrict__ conv_bias,
                         unsigned short* __restrict__ z) {         // [3072][8192]
  __shared__ float2 buf[16384];                              // 128 KB
  const int tid = threadIdx.x;
  const int c   = blockIdx.x;

  // ---- pack: fused depthwise conv3 + pre-gate; batch0 = re, batch1 = im ----
  const int c0 = c % 1152;
  const int c1 = (c + 384) % 1152;
  const int c2 = (c + 768) % 1152;
  const unsigned short* r0 = upT + (size_t)c0 * 16384;
  const unsigned short* r1 = upT + (size_t)c1 * 16384;
  const unsigned short* r2 = upT + (size_t)c2 * 16384;
  float w0[3], w1v[3], w2v[3];
#pragma unroll
  for (int j = 0; j < 3; ++j) {
    w0[j]  = short_w[(size_t)c * 3 + j];
    w1v[j] = short_w[(size_t)(1536 + c) * 3 + j];
    w2v[j] = short_w[(size_t)(3072 + c) * 3 + j];
  }
  const float b0 = short_b[c], b1s = short_b[1536 + c], b2s = short_b[3072 + c];
  float x0a[8], x0b[8], vpa[8], vpb[8];
#pragma unroll
  for (int i = 0; i < 8; ++i) {
    const int n = tid + i * 1024;
    float s0a = b0, s1a = b1s, s2a = b2s;
    float s0b = b0, s1b = b1s, s2b = b2s;
#pragma unroll
    for (int j = 0; j < 3; ++j) {
      const int t = n - 2 + j;
      if (t >= 0) {
        s0a += w0[j]  * bfu2f(r0[t]);
        s1a += w1v[j] * bfu2f(r1[t]);
        s2a += w2v[j] * bfu2f(r2[t]);
        s0b += w0[j]  * bfu2f(r0[8192 + t]);
        s1b += w1v[j] * bfu2f(r1[8192 + t]);
        s2b += w2v[j] * bfu2f(r2[8192 + t]);
      }
    }
    x0a[i] = s0a; x0b[i] = s0b;
    vpa[i] = s2a * s1a; vpb[i] = s2b * s1b;
    buf[SW(n)] = make_float2(vpa[i], vpb[i]);
  }
#pragma unroll
  for (int i = 8; i < 16; ++i) buf[SW(tid + i * 1024)] = make_float2(0.f, 0.f);
  __syncthreads();
  dif_fft<1024>(buf, tid);

  // ---- streamed pointwise *K at RAW physical index; conj for DIT-inverse ---
  {
    const size_t kb = (size_t)c * 16384;
#pragma unroll 4
    for (int i = 0; i < 16; ++i) {
      const int n = tid + i * 1024;
      float2 kv;
      if (KF_BF16) {
        const ushort2 kh = ((const ushort2*)Kf)[kb + n];
        kv = make_float2(bfu2f(kh.x), bfu2f(kh.y));
      } else {
        kv = ((const float2*)Kf)[kb + n];
      }
      const float2 a = buf[n];
      buf[n] = make_float2(a.x * kv.x - a.y * kv.y, -(a.x * kv.y + a.y * kv.x));
    }
  }
  __syncthreads();
  dit_fft<1024>(buf, tid);

  // ---- finalize: y = conj(F)/N ; conv_bias skip ; post-gate by x0 ----
  const float cb  = conv_bias[c];
  const float inv = 1.0f / 16384.0f;
  unsigned short* za = z + (size_t)c * 8192;
  unsigned short* zb = z + (size_t)(1536 + c) * 8192;
#pragma unroll
  for (int i = 0; i < 8; ++i) {
    const int n = tid + i * 1024;
    const float2 F = buf[SW(n)];
    const float ya =  F.x * inv;
    const float yb = -F.y * inv;
    za[n] = f2bf((ya + vpa[i] * cb) * x0a[i]);
    zb[n] = f2bf((yb + vpb[i] * cb) * x0b[i]);
  }
}

// ---------------- fallback monolithic (512 thr, K-FFT in-kernel) ------------
__global__ __launch_bounds__(512)
void hyena_fftconv_mono(const unsigned short* __restrict__ upT,
                        const float* __restrict__ kmat,
                        const float* __restrict__ short_w,
                        const float* __restrict__ short_b,
                        const float* __restrict__ conv_bias,
                        unsigned short* __restrict__ z) {
  __shared__ float2 buf[16384];
  const int tid = threadIdx.x;
  const int c   = blockIdx.x;

  const float* kr = kmat + (size_t)c * 8192;
#pragma unroll
  for (int i = 0; i < 32; ++i) {
    const int n = tid + i * 512;
    float2 v = make_float2(0.f, 0.f);
    if (n < 8192) v.x = kr[n];
    buf[SW(n)] = v;
  }
  __syncthreads();
  dif_fft<512>(buf, tid);
  float2 kf[32];
#pragma unroll
  for (int i = 0; i < 32; ++i) kf[i] = buf[tid + i * 512];
  __syncthreads();

  const int c0 = c % 1152;
  const int c1 = (c + 384) % 1152;
  const int c2 = (c + 768) % 1152;
  const unsigned short* r0 = upT + (size_t)c0 * 16384;
  const unsigned short* r1 = upT + (size_t)c1 * 16384;
  const unsigned short* r2 = upT + (size_t)c2 * 16384;
  float w0[3], w1v[3], w2v[3];
#pragma unroll
  for (int j = 0; j < 3; ++j) {
    w0[j]  = short_w[(size_t)c * 3 + j];
    w1v[j] = short_w[(size_t)(1536 + c) * 3 + j];
    w2v[j] = short_w[(size_t)(3072 + c) * 3 + j];
  }
  const float b0 = short_b[c], b1s = short_b[1536 + c], b2s = short_b[3072 + c];
  float x0a[16], x0b[16], vpa[16], vpb[16];
#pragma unroll
  for (int i = 0; i < 16; ++i) {
    const int n = tid + i * 512;
    float s0a = b0, s1a = b1s, s2a = b2s;
    float s0b = b0, s1b = b1s, s2b = b2s;
#pragma unroll
    for (int j = 0; j < 3; ++j) {
      const int t = n - 2 + j;
      if (t >= 0) {
        s0a += w0[j]  * bfu2f(r0[t]);
        s1a += w1v[j] * bfu2f(r1[t]);
        s2a += w2v[j] * bfu2f(r2[t]);
        s0b += w0[j]  * bfu2f(r0[8192 + t]);
        s1b += w1v[j] * bfu2f(r1[8192 + t]);
        s2b += w2v[j] * bfu2f(r2[8192 + t]);
      }
    }
    x0a[i] = s0a; x0b[i] = s0b;
    vpa[i] = s2a * s1a; vpb[i] = s2b * s1b;
    buf[SW(n)] = make_float2(vpa[i], vpb[i]);
  }
#pragma unroll
  for (int i = 16; i < 32; ++i) buf[SW(tid + i * 512)] = make_float2(0.f, 0.f);
  __syncthreads();
  dif_fft<512>(buf, tid);

#pragma unroll
  for (int i = 0; i < 32; ++i) {
    const int n = tid + i * 512;
    const float2 a = buf[n], b = kf[i];
    buf[n] = make_float2(a.x * b.x - a.y * b.y, -(a.x * b.y + a.y * b.x));
  }
  __syncthreads();
  dit_fft<512>(buf, tid);

  const float cb  = conv_bias[c];
  const float inv = 1.0f / 16384.0f;
  unsigned short* za = z + (size_t)c * 8192;
  unsigned short* zb = z + (size_t)(1536 + c) * 8192;
#pragma unroll
  for (int i = 0; i < 16; ++i) {
    const int n = tid + i * 512;
    const float2 F = buf[SW(n)];
    const float ya =  F.x * inv;
    const float yb = -F.y * inv;
    za[n] = f2bf((ya + vpa[i] * cb) * x0a[i]);
    zb[n] = f2bf((yb + vpb[i] * cb) * x0b[i]);
  }
}

// ---------------- transpose z[3072][8192] -> zt[16384][1536] ----------------
__global__ __launch_bounds__(256)
void transpose_z(const unsigned short* __restrict__ z, unsigned short* __restrict__ zt) {
  __shared__ unsigned short tile[64][65];
  const int tid = threadIdx.x;
  const int ct = blockIdx.x;
  const int tt = blockIdx.y;
  const int b  = blockIdx.z;
#pragma unroll
  for (int p = 0; p < 2; ++p) {
    const int idx = p * 256 + tid;
    const int row = idx >> 3;
    const int c8  = idx & 7;
    const uint4 v = *(const uint4*)(z + (size_t)(b * 1536 + ct * 64 + row) * 8192 + tt * 64 + c8 * 8);
    unsigned short* tp = &tile[row][c8 * 8];
    tp[0] = (unsigned short)(v.x & 0xffff); tp[1] = (unsigned short)(v.x >> 16);
    tp[2] = (unsigned short)(v.y & 0xffff); tp[3] = (unsigned short)(v.y >> 16);
    tp[4] = (unsigned short)(v.z & 0xffff); tp[5] = (unsigned short)(v.z >> 16);
    tp[6] = (unsigned short)(v.w & 0xffff); tp[7] = (unsigned short)(v.w >> 16);
  }
  __syncthreads();
#pragma unroll
  for (int p = 0; p < 2; ++p) {
    const int idx  = p * 256 + tid;
    const int trow = idx >> 3;
    const int cc   = idx & 7;
    uint4 o;
    o.x = (unsigned)tile[cc * 8 + 0][trow] | ((unsigned)tile[cc * 8 + 1][trow] << 16);
    o.y = (unsigned)tile[cc * 8 + 2][trow] | ((unsigned)tile[cc * 8 + 3][trow] << 16);
    o.z = (unsigned)tile[cc * 8 + 4][trow] | ((unsigned)tile[cc * 8 + 5][trow] << 16);
    o.w = (unsigned)tile[cc * 8 + 6][trow] | ((unsigned)tile[cc * 8 + 7][trow] << 16);
    *(uint4*)(zt + (size_t)(b * 8192 + tt * 64 + trow) * 1536 + ct * 64 + cc * 8) = o;
  }
}

// ---------------------------------------------------------------------------
extern "C" void kernel_launch(void* const* d_in, const int* in_sizes, int n_in,
                              void* d_out, int out_size, void* d_ws, size_t ws_size,
                              hipStream_t stream) {
  const float* u   = (const float*)d_in[0];
  const float* w1  = (const float*)d_in[1];
  const float* b1  = (const float*)d_in[2];
  const float* sw  = (const float*)d_in[3];
  const float* sb  = (const float*)d_in[4];
  const float* km  = (const float*)d_in[5];
  const float* cb  = (const float*)d_in[6];
  const float* w2  = (const float*)d_in[7];
  const float* b2  = (const float*)d_in[8];
  float* outp = (float*)d_out;

  char* ws = (char*)d_ws;
  // layout (bytes):
  constexpr size_t OFF_UBF  = 0;                       // 25165824
  constexpr size_t OFF_W1   = 25165824;                //  1769472
  constexpr size_t OFF_W2   = 26935296;                //  2359296
  constexpr size_t OFF_UPT  = 29294592;                // 37748736
  constexpr size_t OFF_ZBUF = 67043328;                // 50331648
  constexpr size_t OFF_KF   = 117374976;               // Kf; ztb aliases here
  constexpr size_t OFF_ZTB  = 117374976;               // 50331648
  constexpr size_t KF_F32   = 201326592;               // 16384*8*1536
  constexpr size_t KF_BF16  = 100663296;

  unsigned short* u_bf  = (unsigned short*)(ws + OFF_UBF);
  unsigned short* w1_bf = (unsigned short*)(ws + OFF_W1);
  unsigned short* w2_bf = (unsigned short*)(ws + OFF_W2);
  unsigned short* upT   = (unsigned short*)(ws + OFF_UPT);
  unsigned short* zbuf  = (unsigned short*)(ws + OFF_ZBUF);
  void*           kfbuf = (void*)(ws + OFF_KF);
  unsigned short* ztb   = (unsigned short*)(ws + OFF_ZTB);

  cast_f32_to_bf16<<<12288, 256, 0, stream>>>(u,  u_bf,  12582912);
  cast_f32_to_bf16<<<  864, 256, 0, stream>>>(w1, w1_bf,   884736);
  cast_f32_to_bf16<<< 1152, 256, 0, stream>>>(w2, w2_bf,  1179648);

  dim3 g1(128, 9);
  gemm_bt<1><<<g1, 256, 0, stream>>>(u_bf, w1_bf, b1, upT, 16384, 1152, 768);

  if (ws_size >= OFF_KF + KF_F32) {
    fft_k_kernel<0><<<1536, 1024, 0, stream>>>(km, kfbuf);
    hyena_fftconv_split<0><<<1536, 1024, 0, stream>>>(upT, kfbuf, sw, sb, cb, zbuf);
  } else if (ws_size >= OFF_KF + KF_BF16) {
    fft_k_kernel<1><<<1536, 1024, 0, stream>>>(km, kfbuf);
    hyena_fftconv_split<1><<<1536, 1024, 0, stream>>>(upT, kfbuf, sw, sb, cb, zbuf);
  } else {
    hyena_fftconv_mono<<<1536, 512, 0, stream>>>(upT, km, sw, sb, cb, zbuf);
  }

  transpose_z<<<dim3(24, 128, 2), 256, 0, stream>>>(zbuf, ztb);

  dim3 g2(128, 6);
  gemm_bt<0><<<g2, 256, 0, stream>>>(ztb, w2_bf, b2, outp, 16384, 768, 1536);
}

// Round 4
// 440.672 us; speedup vs baseline: 1.3204x; 1.1047x over previous
//
#include <hip/hip_runtime.h>
#include <cstdint>
#include <cstddef>

// ---------------------------------------------------------------------------
// Hyena operator, MI355X.
//  cast(u,W1,W2)->bf16 ; GEMM1 (bf16 MFMA, writes upT[1152][16384] bf16 +bias)
//  fft_k: per channel, radix-16 DIF FFT of zero-padded k_c; stores
//         Kf'' = (Kf + conv_bias)/N RAW (physical slot layout) to workspace.
//  fftconv_split: pack (depthwise conv3 + pre-gate, batches as re/im, regs)
//         -> trips A,B,C fwd -> fused[D fwd, xKf'', D inv] in regs
//         -> trips C',B' inv -> A' inv in regs -> finalize (post-gate x0).
//  transpose z -> zt ; GEMM2 (bf16 MFMA, f32 out+bias) -> d_out
// ---------------------------------------------------------------------------

using s16x8 = __attribute__((ext_vector_type(8))) short;
using f32x4 = __attribute__((ext_vector_type(4))) float;

__device__ __forceinline__ float bfu2f(unsigned short h) {
  union { unsigned int u; float f; } a; a.u = ((unsigned int)h) << 16; return a.f;
}
__device__ __forceinline__ unsigned short f2bf(float f) {
  union { float f; unsigned int u; } a; a.f = f;
  unsigned int r = a.u + 0x7fffu + ((a.u >> 16) & 1u);
  return (unsigned short)(r >> 16);
}
__device__ __forceinline__ float2 cmul(float2 a, float2 b) {
  return make_float2(a.x*b.x - a.y*b.y, a.x*b.y + a.y*b.x);
}
__device__ __forceinline__ float2 cmulc(float2 a, float cr, float ci) {
  return make_float2(a.x*cr - a.y*ci, a.x*ci + a.y*cr);
}
__device__ __forceinline__ float2 cadd(float2 a, float2 b) { return make_float2(a.x+b.x, a.y+b.y); }
__device__ __forceinline__ float2 csub(float2 a, float2 b) { return make_float2(a.x-b.x, a.y-b.y); }
// LDS bank swizzle at float2 granularity (involution, bits 4..7 preserved).
__device__ __forceinline__ int SW(int p) { return p ^ ((p >> 4) & 15); }

#define TWOPI 6.2831853071795864769f

// ---------------- cast f32 -> bf16 ----------------
__global__ __launch_bounds__(256)
void cast_f32_to_bf16(const float* __restrict__ src, unsigned short* __restrict__ dst, const int n) {
  const int i = (blockIdx.x * 256 + threadIdx.x) * 4;
  if (i < n) {
    const float4 v = *(const float4*)(src + i);
    ushort4 o;
    o.x = f2bf(v.x); o.y = f2bf(v.y); o.z = f2bf(v.z); o.w = f2bf(v.w);
    *(ushort4*)(dst + i) = o;
  }
}

// ---------------- bf16 GEMM: C[m][n] = sum_k A[m][k]*B[n][k] + bias[n] ------
template<int TRANS>
__global__ __launch_bounds__(256)
void gemm_bt(const unsigned short* __restrict__ A, const unsigned short* __restrict__ B,
             const float* __restrict__ bias, void* __restrict__ Cout,
             const int M, const int N, const int K) {
  __shared__ unsigned short As[128 * 32];
  __shared__ unsigned short Bs[128 * 32];
  const int tid  = threadIdx.x;
  const int lane = tid & 63;
  const int wave = tid >> 6;
  const int m0 = blockIdx.x * 128;
  const int n0 = blockIdx.y * 128;
  const int wm = (wave >> 1) * 64;
  const int wn = (wave & 1) * 64;
  f32x4 acc[4][4] = {};

  const int srow = lane >> 2;
  const int scol = (lane & 3) * 8;

  for (int k0 = 0; k0 < K; k0 += 32) {
    __syncthreads();
#pragma unroll
    for (int pass = 0; pass < 2; ++pass) {
      const int rbase = pass * 64 + wave * 16;
      const unsigned short* ga = A + (size_t)(m0 + rbase + srow) * K + k0 + scol;
      const unsigned short* gb = B + (size_t)(n0 + rbase + srow) * K + k0 + scol;
      __builtin_amdgcn_global_load_lds((__attribute__((address_space(1))) void*)ga,
                                       (__attribute__((address_space(3))) void*)(As + rbase * 32), 16, 0, 0);
      __builtin_amdgcn_global_load_lds((__attribute__((address_space(1))) void*)gb,
                                       (__attribute__((address_space(3))) void*)(Bs + rbase * 32), 16, 0, 0);
    }
    __syncthreads();
    s16x8 af[4], bfr[4];
#pragma unroll
    for (int i = 0; i < 4; ++i) {
      af[i]  = *(const s16x8*)(As + (wm + i * 16 + (lane & 15)) * 32 + (lane >> 4) * 8);
      bfr[i] = *(const s16x8*)(Bs + (wn + i * 16 + (lane & 15)) * 32 + (lane >> 4) * 8);
    }
#pragma unroll
    for (int mi = 0; mi < 4; ++mi)
#pragma unroll
      for (int ni = 0; ni < 4; ++ni)
        acc[mi][ni] = __builtin_amdgcn_mfma_f32_16x16x32_bf16(af[mi], bfr[ni], acc[mi][ni], 0, 0, 0);
  }
#pragma unroll
  for (int mi = 0; mi < 4; ++mi) {
#pragma unroll
    for (int ni = 0; ni < 4; ++ni) {
      const int col  = n0 + wn + ni * 16 + (lane & 15);
      const int row0 = m0 + wm + mi * 16 + (lane >> 4) * 4;
      const float bv = bias[col];
      if (TRANS) {
        unsigned short* Ct = (unsigned short*)Cout;
        ushort4 o;
        o.x = f2bf(acc[mi][ni][0] + bv);
        o.y = f2bf(acc[mi][ni][1] + bv);
        o.z = f2bf(acc[mi][ni][2] + bv);
        o.w = f2bf(acc[mi][ni][3] + bv);
        *(ushort4*)(Ct + (size_t)col * M + row0) = o;
      } else {
        float* C = (float*)Cout;
#pragma unroll
        for (int rr = 0; rr < 4; ++rr)
          C[(size_t)(row0 + rr) * N + col] = acc[mi][ni][rr] + bv;
      }
    }
  }
}

// =================== radix-16 FFT building blocks ===========================
template<int SGN>   // -1: fwd (w=e^{-2pi i/4}=-i), +1: inv (+i)
__device__ __forceinline__ void dft4(float2& a, float2& b, float2& c, float2& d) {
  const float2 t0 = cadd(a, c), t1 = csub(a, c);
  const float2 t2 = cadd(b, d), t3 = csub(b, d);
  const float2 jt3 = (SGN < 0) ? make_float2(t3.y, -t3.x) : make_float2(-t3.y, t3.x);
  a = cadd(t0, t2);
  c = csub(t0, t2);
  b = cadd(t1, jt3);
  d = csub(t1, jt3);
}
// inputs c,d known zero (never read); outputs X0..X3 -> a,b,c,d
template<int SGN>
__device__ __forceinline__ void dft4_half(float2& a, float2& b, float2& c, float2& d) {
  const float2 a0 = a, b0 = b;
  const float2 jb = (SGN < 0) ? make_float2(b0.y, -b0.x) : make_float2(-b0.y, b0.x);
  a = cadd(a0, b0);
  c = csub(a0, b0);
  b = cadd(a0, jb);
  d = csub(a0, jb);
}
// only X0, X1 produced (into a, b)
template<int SGN>
__device__ __forceinline__ void dft4_lo(float2& a, float2& b, const float2 c, const float2 d) {
  const float2 t0 = cadd(a, c), t1 = csub(a, c);
  const float2 t2 = cadd(b, d), t3 = csub(b, d);
  const float2 jt3 = (SGN < 0) ? make_float2(t3.y, -t3.x) : make_float2(-t3.y, t3.x);
  a = cadd(t0, t2);
  b = cadd(t1, jt3);
}

// 16-point DFT, 4x4 decomposition. Input x_m at y[m] (natural); output
// X[4k1+k0] lands at y[4k0+k1] (digit swap, handled by callers).
template<int SGN, bool HALFIN, bool LO8>
__device__ __forceinline__ void dft16_core(float2* y) {
#pragma unroll
  for (int m0 = 0; m0 < 4; ++m0) {
    if (HALFIN) dft4_half<SGN>(y[m0], y[4+m0], y[8+m0], y[12+m0]);
    else        dft4<SGN>(y[m0], y[4+m0], y[8+m0], y[12+m0]);
  }
  const float sg = (SGN < 0) ? -1.f : 1.f;
  const float C_ = 0.92387953251128675613f;
  const float S_ = 0.38268343236508977173f;
  const float R_ = 0.70710678118654752440f;
  y[5]  = cmulc(y[5],  C_,  sg*S_);
  y[6]  = cmulc(y[6],  R_,  sg*R_);
  y[7]  = cmulc(y[7],  S_,  sg*C_);
  y[9]  = cmulc(y[9],  R_,  sg*R_);
  y[10] = (SGN < 0) ? make_float2(y[10].y, -y[10].x) : make_float2(-y[10].y, y[10].x);
  y[11] = cmulc(y[11], -R_, sg*R_);
  y[13] = cmulc(y[13], S_,  sg*C_);
  y[14] = cmulc(y[14], -R_, sg*R_);
  y[15] = cmulc(y[15], -C_, -sg*S_);
#pragma unroll
  for (int k0 = 0; k0 < 4; ++k0) {
    if (LO8) dft4_lo<SGN>(y[4*k0], y[4*k0+1], y[4*k0+2], y[4*k0+3]);
    else     dft4<SGN>(y[4*k0], y[4*k0+1], y[4*k0+2], y[4*k0+3]);
  }
}

// W[k] = (cos ang, sin ang)^k, k=1..15 via power tree
__device__ __forceinline__ void make_W(float2* W, float ang) {
  float sn, cs; __sincosf(ang, &sn, &cs);
  W[1] = make_float2(cs, sn);
  W[2] = cmul(W[1], W[1]);
  W[3] = cmul(W[2], W[1]);
  W[4] = cmul(W[2], W[2]);
  W[5] = cmul(W[4], W[1]);
  W[6] = cmul(W[4], W[2]);
  W[7] = cmul(W[4], W[3]);
  W[8] = cmul(W[4], W[4]);
#pragma unroll
  for (int k = 9; k < 16; ++k) W[k] = cmul(W[8], W[k-8]);
}

// middle forward trip: stride S=2^LOGS, block M=2^LOGM, 1024 groups
template<int LOGS, int LOGM>
__device__ __forceinline__ void trip_fwd(float2* __restrict__ buf, const int tid) {
  const int j = tid & ((1 << LOGS) - 1);
  const int base = ((tid >> LOGS) << LOGM) + j;
  float2 y[16];
#pragma unroll
  for (int m = 0; m < 16; ++m) y[m] = buf[SW(base + (m << LOGS))];
  dft16_core<-1, false, false>(y);
  float2 W[16];
  make_W(W, -TWOPI * (float)j * (1.0f / (float)(1 << LOGM)));
  buf[SW(base)] = y[0];
#pragma unroll
  for (int k = 1; k < 16; ++k)
    buf[SW(base + (k << LOGS))] = cmul(y[4*(k&3) + (k>>2)], W[k]);
}

template<int LOGS, int LOGM>
__device__ __forceinline__ void trip_inv(float2* __restrict__ buf, const int tid) {
  const int j = tid & ((1 << LOGS) - 1);
  const int base = ((tid >> LOGS) << LOGM) + j;
  float2 W[16];
  make_W(W, TWOPI * (float)j * (1.0f / (float)(1 << LOGM)));
  float2 y[16];
  y[0] = buf[SW(base)];
#pragma unroll
  for (int k = 1; k < 16; ++k) y[k] = cmul(buf[SW(base + (k << LOGS))], W[k]);
  dft16_core<1, false, false>(y);
#pragma unroll
  for (int m = 0; m < 16; ++m)
    buf[SW(base + (m << LOGS))] = y[4*(m&3) + (m>>2)];
}

// ---------------- K-spectrum: Kf'' = (FFT(k_pad) + cb) / N, RAW layout ------
template<int KF_BF16>
__attribute__((amdgpu_waves_per_eu(4, 4)))
__global__ __launch_bounds__(1024)
void fft_k_kernel(const float* __restrict__ kmat, const float* __restrict__ conv_bias,
                  void* __restrict__ Kf) {
  __shared__ float2 buf[16384];
  const int tid = threadIdx.x;
  const int c   = blockIdx.x;
  const float* kr = kmat + (size_t)c * 8192;
  // trip A fwd (M=16384, S=1024), upper half zero, input from global
  {
    float2 y[16];
#pragma unroll
    for (int m = 0; m < 8; ++m) y[m] = make_float2(kr[tid + (m << 10)], 0.f);
    dft16_core<-1, true, false>(y);
    float2 W[16];
    make_W(W, -TWOPI * (float)tid * (1.0f / 16384.0f));
    buf[SW(tid)] = y[0];
#pragma unroll
    for (int k = 1; k < 16; ++k)
      buf[SW(tid + (k << 10))] = cmul(y[4*(k&3) + (k>>2)], W[k]);
  }
  __syncthreads();
  trip_fwd<6, 10>(buf, tid);
  __syncthreads();
  trip_fwd<2, 6>(buf, tid);
  __syncthreads();
  // trip D fwd in regs; add cb; scale 1/N; store straight to global
  const float cb  = conv_bias[c];
  const float inv = 1.0f / 16384.0f;
#pragma unroll
  for (int it = 0; it < 4; ++it) {
    const int base = 4 * (tid + (it << 10));
    float2 a = buf[SW(base)], b = buf[SW(base+1)], e = buf[SW(base+2)], d = buf[SW(base+3)];
    dft4<-1>(a, b, e, d);
    if (KF_BF16) {
      ushort2* o = (ushort2*)Kf + (size_t)c * 16384 + base;
      uint4 hv;
      hv.x = (unsigned)f2bf((a.x + cb) * inv) | ((unsigned)f2bf(a.y * inv) << 16);
      hv.y = (unsigned)f2bf((b.x + cb) * inv) | ((unsigned)f2bf(b.y * inv) << 16);
      hv.z = (unsigned)f2bf((e.x + cb) * inv) | ((unsigned)f2bf(e.y * inv) << 16);
      hv.w = (unsigned)f2bf((d.x + cb) * inv) | ((unsigned)f2bf(d.y * inv) << 16);
      *(uint4*)o = hv;
    } else {
      float4* o = (float4*)((float2*)Kf + (size_t)c * 16384 + base);
      o[0] = make_float4((a.x + cb) * inv, a.y * inv, (b.x + cb) * inv, b.y * inv);
      o[1] = make_float4((e.x + cb) * inv, e.y * inv, (d.x + cb) * inv, d.y * inv);
    }
  }
}

// ---------------- main fused kernel -----------------------------------------
template<int KF_BF16>
__attribute__((amdgcn_unused)) __device__ int _dummy_decl;  // (no-op placeholder)

template<int KF_BF16>
__attribute__((amdgpu_waves_per_eu(4, 4)))
__global__ __launch_bounds__(1024)
void hyena_fftconv_split(const unsigned short* __restrict__ upT,  // [1152][16384]
                         const void* __restrict__ Kf,
                         const float* __restrict__ short_w,
                         const float* __restrict__ short_b,
                         unsigned short* __restrict__ z) {          // [3072][8192]
  __shared__ float2 buf[16384];
  const int tid = threadIdx.x;
  const int c   = blockIdx.x;

  // ---- pack: depthwise conv3 + pre-gate (regs); batch0 = re, batch1 = im ---
  const int c0 = c % 1152;
  const int c1 = (c + 384) % 1152;
  const int c2 = (c + 768) % 1152;
  const unsigned short* r0 = upT + (size_t)c0 * 16384;
  const unsigned short* r1 = upT + (size_t)c1 * 16384;
  const unsigned short* r2 = upT + (size_t)c2 * 16384;
  float w0[3], w1v[3], w2v[3];
#pragma unroll
  for (int j = 0; j < 3; ++j) {
    w0[j]  = short_w[(size_t)c * 3 + j];
    w1v[j] = short_w[(size_t)(1536 + c) * 3 + j];
    w2v[j] = short_w[(size_t)(3072 + c) * 3 + j];
  }
  const float b0 = short_b[c], b1s = short_b[1536 + c], b2s = short_b[3072 + c];
  float2 xy[8];
  unsigned x0p[8];   // packed bf16 gates (lo=batch0, hi=batch1)
#pragma unroll
  for (int i = 0; i < 8; ++i) {
    const int n = tid + (i << 10);
    float s0a = b0, s1a = b1s, s2a = b2s;
    float s0b = b0, s1b = b1s, s2b = b2s;
#pragma unroll
    for (int j = 0; j < 3; ++j) {
      const int t = n - 2 + j;
      if (t >= 0) {
        s0a += w0[j]  * bfu2f(r0[t]);
        s1a += w1v[j] * bfu2f(r1[t]);
        s2a += w2v[j] * bfu2f(r2[t]);
        s0b += w0[j]  * bfu2f(r0[8192 + t]);
        s1b += w1v[j] * bfu2f(r1[8192 + t]);
        s2b += w2v[j] * bfu2f(r2[8192 + t]);
      }
    }
    xy[i] = make_float2(s2a * s1a, s2b * s1b);
    x0p[i] = (unsigned)f2bf(s0a) | ((unsigned)f2bf(s0b) << 16);
  }

  // ---- trip A fwd (M=16384, S=1024), input from regs, upper half zero ----
  {
    float2 y[16];
#pragma unroll
    for (int m = 0; m < 8; ++m) y[m] = xy[m];
    dft16_core<-1, true, false>(y);
    float2 W[16];
    make_W(W, -TWOPI * (float)tid * (1.0f / 16384.0f));
    buf[SW(tid)] = y[0];
#pragma unroll
    for (int k = 1; k < 16; ++k)
      buf[SW(tid + (k << 10))] = cmul(y[4*(k&3) + (k>>2)], W[k]);
  }
  __syncthreads();
  trip_fwd<6, 10>(buf, tid);
  __syncthreads();
  trip_fwd<2, 6>(buf, tid);
  __syncthreads();

  // ---- fused: trip D fwd -> pointwise * Kf'' -> trip D inv (all regs) ----
#pragma unroll
  for (int it = 0; it < 4; ++it) {
    const int base = 4 * (tid + (it << 10));
    float2 a = buf[SW(base)], b = buf[SW(base+1)], e = buf[SW(base+2)], d = buf[SW(base+3)];
    dft4<-1>(a, b, e, d);
    float2 k0v, k1v, k2v, k3v;
    if (KF_BF16) {
      const uint4 hv = *(const uint4*)((const ushort2*)Kf + (size_t)c * 16384 + base);
      k0v = make_float2(bfu2f((unsigned short)(hv.x & 0xffff)), bfu2f((unsigned short)(hv.x >> 16)));
      k1v = make_float2(bfu2f((unsigned short)(hv.y & 0xffff)), bfu2f((unsigned short)(hv.y >> 16)));
      k2v = make_float2(bfu2f((unsigned short)(hv.z & 0xffff)), bfu2f((unsigned short)(hv.z >> 16)));
      k3v = make_float2(bfu2f((unsigned short)(hv.w & 0xffff)), bfu2f((unsigned short)(hv.w >> 16)));
    } else {
      const float4* k4 = (const float4*)((const float2*)Kf + (size_t)c * 16384 + base);
      const float4 A = k4[0], B = k4[1];
      k0v = make_float2(A.x, A.y); k1v = make_float2(A.z, A.w);
      k2v = make_float2(B.x, B.y); k3v = make_float2(B.z, B.w);
    }
    a = cmul(a, k0v); b = cmul(b, k1v); e = cmul(e, k2v); d = cmul(d, k3v);
    dft4<1>(a, b, e, d);
    buf[SW(base)] = a; buf[SW(base+1)] = b; buf[SW(base+2)] = e; buf[SW(base+3)] = d;
  }
  __syncthreads();
  trip_inv<2, 6>(buf, tid);
  __syncthreads();
  trip_inv<6, 10>(buf, tid);
  __syncthreads();

  // ---- trip A' inv (LDS -> regs, only m<8 needed) + finalize ----
  {
    float2 W[16];
    make_W(W, TWOPI * (float)tid * (1.0f / 16384.0f));
    float2 y[16];
    y[0] = buf[SW(tid)];
#pragma unroll
    for (int k = 1; k < 16; ++k) y[k] = cmul(buf[SW(tid + (k << 10))], W[k]);
    dft16_core<1, false, true>(y);
    unsigned short* za = z + (size_t)c * 8192;
    unsigned short* zb = z + (size_t)(1536 + c) * 8192;
#pragma unroll
    for (int m = 0; m < 8; ++m) {
      const float2 F = y[4*(m&3) + (m>>2)];
      const float xa = bfu2f((unsigned short)(x0p[m] & 0xffff));
      const float xb = bfu2f((unsigned short)(x0p[m] >> 16));
      za[tid + (m << 10)] = f2bf(F.x * xa);
      zb[tid + (m << 10)] = f2bf(F.y * xb);
    }
  }
}

// =============== legacy radix-4 (fallback mono path only) ===================
__device__ __forceinline__ void dif_bfly(float2* __restrict__ buf, const int p0, const int q,
                                         const float2 w1, const float2 w2) {
  float2 x0 = buf[SW(p0)];
  float2 x1 = buf[SW(p0 + q)];
  float2 x2 = buf[SW(p0 + 2 * q)];
  float2 x3 = buf[SW(p0 + 3 * q)];
  const float2 ta = cadd(x0, x2), tb = csub(x0, x2);
  const float2 ua = cadd(x1, x3), ub = csub(x1, x3);
  const float2 v02 = cmul(tb, w1);
  float2 v13 = cmul(ub, w1);
  v13 = make_float2(v13.y, -v13.x);
  buf[SW(p0)]         = cadd(ta, ua);
  buf[SW(p0 + q)]     = cmul(csub(ta, ua), w2);
  buf[SW(p0 + 2 * q)] = cadd(v02, v13);
  buf[SW(p0 + 3 * q)] = cmul(csub(v02, v13), w2);
}
__device__ __forceinline__ void dit_bfly(float2* __restrict__ buf, const int p0, const int q,
                                         const float2 w1, const float2 w2) {
  float2 x0 = buf[SW(p0)];
  float2 x1 = buf[SW(p0 + q)];
  float2 x2 = buf[SW(p0 + 2 * q)];
  float2 x3 = buf[SW(p0 + 3 * q)];
  const float2 t1 = cmul(x1, w2);
  const float2 y0 = cadd(x0, t1), y1 = csub(x0, t1);
  const float2 t3 = cmul(x3, w2);
  const float2 y2 = cadd(x2, t3), y3 = csub(x2, t3);
  const float2 t  = cmul(y2, w1);
  float2 t4 = cmul(y3, w1);
  t4 = make_float2(t4.y, -t4.x);
  buf[SW(p0)]         = cadd(y0, t);
  buf[SW(p0 + q)]     = cadd(y1, t4);
  buf[SW(p0 + 2 * q)] = csub(y0, t);
  buf[SW(p0 + 3 * q)] = csub(y1, t4);
}
template<int NTHR>
__device__ __forceinline__ void dif_fft(float2* __restrict__ buf, const int tid) {
  constexpr int ITERS = 4096 / NTHR;
  for (int r = 0; r < 7; ++r) {
    const int qs = 12 - 2 * r;
    const int q  = 1 << qs;
    const float angf = -TWOPI / (float)(4 << qs);
    if (q <= NTHR) {
      const int j = tid & (q - 1);
      float sn, cs; __sincosf(angf * (float)j, &sn, &cs);
      const float2 w1 = make_float2(cs, sn);
      const float2 w2 = cmul(w1, w1);
#pragma unroll
      for (int it = 0; it < ITERS; ++it) {
        const int id = tid + it * NTHR;
        const int p0 = ((id >> qs) << (qs + 2)) + j;
        dif_bfly(buf, p0, q, w1, w2);
      }
    } else {
#pragma unroll
      for (int it = 0; it < ITERS; ++it) {
        const int id = tid + it * NTHR;
        const int j  = id & (q - 1);
        const int p0 = ((id >> qs) << (qs + 2)) + j;
        float sn, cs; __sincosf(angf * (float)j, &sn, &cs);
        const float2 w1 = make_float2(cs, sn);
        dif_bfly(buf, p0, q, w1, cmul(w1, w1));
      }
    }
    __syncthreads();
  }
}
template<int NTHR>
__device__ __forceinline__ void dit_fft(float2* __restrict__ buf, const int tid) {
  constexpr int ITERS = 4096 / NTHR;
  for (int r = 0; r < 7; ++r) {
    const int qs = 2 * r;
    const int q  = 1 << qs;
    const float angf = -TWOPI / (float)(4 << qs);
    if (q <= NTHR) {
      const int j = tid & (q - 1);
      float sn, cs; __sincosf(angf * (float)j, &sn, &cs);
      const float2 w1 = make_float2(cs, sn);
      const float2 w2 = cmul(w1, w1);
#pragma unroll
      for (int it = 0; it < ITERS; ++it) {
        const int id = tid + it * NTHR;
        const int p0 = ((id >> qs) << (qs + 2)) + j;
        dit_bfly(buf, p0, q, w1, w2);
      }
    } else {
#pragma unroll
      for (int it = 0; it < ITERS; ++it) {
        const int id = tid + it * NTHR;
        const int j  = id & (q - 1);
        const int p0 = ((id >> qs) << (qs + 2)) + j;
        float sn, cs; __sincosf(angf * (float)j, &sn, &cs);
        const float2 w1 = make_float2(cs, sn);
        dit_bfly(buf, p0, q, w1, cmul(w1, w1));
      }
    }
    __syncthreads();
  }
}
__global__ __launch_bounds__(512)
void hyena_fftconv_mono(const unsigned short* __restrict__ upT,
                        const float* __restrict__ kmat,
                        const float* __restrict__ short_w,
                        const float* __restrict__ short_b,
                        const float* __restrict__ conv_bias,
                        unsigned short* __restrict__ z) {
  __shared__ float2 buf[16384];
  const int tid = threadIdx.x;
  const int c   = blockIdx.x;
  const float* kr = kmat + (size_t)c * 8192;
#pragma unroll
  for (int i = 0; i < 32; ++i) {
    const int n = tid + i * 512;
    float2 v = make_float2(0.f, 0.f);
    if (n < 8192) v.x = kr[n];
    buf[SW(n)] = v;
  }
  __syncthreads();
  dif_fft<512>(buf, tid);
  float2 kf[32];
#pragma unroll
  for (int i = 0; i < 32; ++i) kf[i] = buf[tid + i * 512];
  __syncthreads();
  const int c0 = c % 1152;
  const int c1 = (c + 384) % 1152;
  const int c2 = (c + 768) % 1152;
  const unsigned short* r0 = upT + (size_t)c0 * 16384;
  const unsigned short* r1 = upT + (size_t)c1 * 16384;
  const unsigned short* r2 = upT + (size_t)c2 * 16384;
  float w0[3], w1v[3], w2v[3];
#pragma unroll
  for (int j = 0; j < 3; ++j) {
    w0[j]  = short_w[(size_t)c * 3 + j];
    w1v[j] = short_w[(size_t)(1536 + c) * 3 + j];
    w2v[j] = short_w[(size_t)(3072 + c) * 3 + j];
  }
  const float b0 = short_b[c], b1s = short_b[1536 + c], b2s = short_b[3072 + c];
  float x0a[16], x0b[16], vpa[16], vpb[16];
#pragma unroll
  for (int i = 0; i < 16; ++i) {
    const int n = tid + i * 512;
    float s0a = b0, s1a = b1s, s2a = b2s;
    float s0b = b0, s1b = b1s, s2b = b2s;
#pragma unroll
    for (int j = 0; j < 3; ++j) {
      const int t = n - 2 + j;
      if (t >= 0) {
        s0a += w0[j]  * bfu2f(r0[t]);
        s1a += w1v[j] * bfu2f(r1[t]);
        s2a += w2v[j] * bfu2f(r2[t]);
        s0b += w0[j]  * bfu2f(r0[8192 + t]);
        s1b += w1v[j] * bfu2f(r1[8192 + t]);
        s2b += w2v[j] * bfu2f(r2[8192 + t]);
      }
    }
    x0a[i] = s0a; x0b[i] = s0b;
    vpa[i] = s2a * s1a; vpb[i] = s2b * s1b;
    buf[SW(n)] = make_float2(vpa[i], vpb[i]);
  }
#pragma unroll
  for (int i = 16; i < 32; ++i) buf[SW(tid + i * 512)] = make_float2(0.f, 0.f);
  __syncthreads();
  dif_fft<512>(buf, tid);
#pragma unroll
  for (int i = 0; i < 32; ++i) {
    const int n = tid + i * 512;
    const float2 a = buf[n], b = kf[i];
    buf[n] = make_float2(a.x * b.x - a.y * b.y, -(a.x * b.y + a.y * b.x));
  }
  __syncthreads();
  dit_fft<512>(buf, tid);
  const float cb  = conv_bias[c];
  const float inv = 1.0f / 16384.0f;
  unsigned short* za = z + (size_t)c * 8192;
  unsigned short* zb = z + (size_t)(1536 + c) * 8192;
#pragma unroll
  for (int i = 0; i < 16; ++i) {
    const int n = tid + i * 512;
    const float2 F = buf[SW(n)];
    za[n] = f2bf((F.x * inv + vpa[i] * cb) * x0a[i]);
    zb[n] = f2bf((-F.y * inv + vpb[i] * cb) * x0b[i]);
  }
}

// ---------------- transpose z[3072][8192] -> zt[16384][1536] ----------------
__global__ __launch_bounds__(256)
void transpose_z(const unsigned short* __restrict__ z, unsigned short* __restrict__ zt) {
  __shared__ unsigned short tile[64][65];
  const int tid = threadIdx.x;
  const int ct = blockIdx.x;
  const int tt = blockIdx.y;
  const int b  = blockIdx.z;
#pragma unroll
  for (int p = 0; p < 2; ++p) {
    const int idx = p * 256 + tid;
    const int row = idx >> 3;
    const int c8  = idx & 7;
    const uint4 v = *(const uint4*)(z + (size_t)(b * 1536 + ct * 64 + row) * 8192 + tt * 64 + c8 * 8);
    unsigned short* tp = &tile[row][c8 * 8];
    tp[0] = (unsigned short)(v.x & 0xffff); tp[1] = (unsigned short)(v.x >> 16);
    tp[2] = (unsigned short)(v.y & 0xffff); tp[3] = (unsigned short)(v.y >> 16);
    tp[4] = (unsigned short)(v.z & 0xffff); tp[5] = (unsigned short)(v.z >> 16);
    tp[6] = (unsigned short)(v.w & 0xffff); tp[7] = (unsigned short)(v.w >> 16);
  }
  __syncthreads();
#pragma unroll
  for (int p = 0; p < 2; ++p) {
    const int idx  = p * 256 + tid;
    const int trow = idx >> 3;
    const int cc   = idx & 7;
    uint4 o;
    o.x = (unsigned)tile[cc * 8 + 0][trow] | ((unsigned)tile[cc * 8 + 1][trow] << 16);
    o.y = (unsigned)tile[cc * 8 + 2][trow] | ((unsigned)tile[cc * 8 + 3][trow] << 16);
    o.z = (unsigned)tile[cc * 8 + 4][trow] | ((unsigned)tile[cc * 8 + 5][trow] << 16);
    o.w = (unsigned)tile[cc * 8 + 6][trow] | ((unsigned)tile[cc * 8 + 7][trow] << 16);
    *(uint4*)(zt + (size_t)(b * 8192 + tt * 64 + trow) * 1536 + ct * 64 + cc * 8) = o;
  }
}

// ---------------------------------------------------------------------------
extern "C" void kernel_launch(void* const* d_in, const int* in_sizes, int n_in,
                              void* d_out, int out_size, void* d_ws, size_t ws_size,
                              hipStream_t stream) {
  const float* u   = (const float*)d_in[0];
  const float* w1  = (const float*)d_in[1];
  const float* b1  = (const float*)d_in[2];
  const float* sw  = (const float*)d_in[3];
  const float* sb  = (const float*)d_in[4];
  const float* km  = (const float*)d_in[5];
  const float* cb  = (const float*)d_in[6];
  const float* w2  = (const float*)d_in[7];
  const float* b2  = (const float*)d_in[8];
  float* outp = (float*)d_out;

  char* ws = (char*)d_ws;
  constexpr size_t OFF_UBF  = 0;
  constexpr size_t OFF_W1   = 25165824;
  constexpr size_t OFF_W2   = 26935296;
  constexpr size_t OFF_UPT  = 29294592;
  constexpr size_t OFF_ZBUF = 67043328;
  constexpr size_t OFF_KF   = 117374976;   // Kf; ztb aliases here (Kf dead by then)
  constexpr size_t OFF_ZTB  = 117374976;
  constexpr size_t KF_F32   = 201326592;
  constexpr size_t KF_BF16  = 100663296;

  unsigned short* u_bf  = (unsigned short*)(ws + OFF_UBF);
  unsigned short* w1_bf = (unsigned short*)(ws + OFF_W1);
  unsigned short* w2_bf = (unsigned short*)(ws + OFF_W2);
  unsigned short* upT   = (unsigned short*)(ws + OFF_UPT);
  unsigned short* zbuf  = (unsigned short*)(ws + OFF_ZBUF);
  void*           kfbuf = (void*)(ws + OFF_KF);
  unsigned short* ztb   = (unsigned short*)(ws + OFF_ZTB);

  cast_f32_to_bf16<<<12288, 256, 0, stream>>>(u,  u_bf,  12582912);
  cast_f32_to_bf16<<<  864, 256, 0, stream>>>(w1, w1_bf,   884736);
  cast_f32_to_bf16<<< 1152, 256, 0, stream>>>(w2, w2_bf,  1179648);

  dim3 g1(128, 9);
  gemm_bt<1><<<g1, 256, 0, stream>>>(u_bf, w1_bf, b1, upT, 16384, 1152, 768);

  if (ws_size >= OFF_KF + KF_F32) {
    fft_k_kernel<0><<<1536, 1024, 0, stream>>>(km, cb, kfbuf);
    hyena_fftconv_split<0><<<1536, 1024, 0, stream>>>(upT, kfbuf, sw, sb, zbuf);
  } else if (ws_size >= OFF_KF + KF_BF16) {
    fft_k_kernel<1><<<1536, 1024, 0, stream>>>(km, cb, kfbuf);
    hyena_fftconv_split<1><<<1536, 1024, 0, stream>>>(upT, kfbuf, sw, sb, zbuf);
  } else {
    hyena_fftconv_mono<<<1536, 512, 0, stream>>>(upT, km, sw, sb, cb, zbuf);
  }

  transpose_z<<<dim3(24, 128, 2), 256, 0, stream>>>(zbuf, ztb);

  dim3 g2(128, 6);
  gemm_bt<0><<<g2, 256, 0, stream>>>(ztb, w2_bf, b2, outp, 16384, 768, 1536);
}